// Round 3
// baseline (248.565 us; speedup 1.0000x reference)
//
#include <hip/hip_runtime.h>
#include <stdint.h>

// Problem constants (B=2,S=2048 -> BS=4096). ALL inputs/outputs are FP32.
#define BSZ   4096    // B*S tokens
#define DIM   1024    // D
#define WTR   4096    // W trees
#define KDIM  4096    // GEMM K == W
#define W8    32768   // W*8 leaf-rows

typedef unsigned short u16;
typedef __attribute__((ext_vector_type(8))) short bhalf8;     // 8 x bf16 (4 VGPRs)
typedef __attribute__((ext_vector_type(4))) float floatx4;    // 16x16 MFMA acc
typedef __attribute__((ext_vector_type(16))) float floatx16;  // 32x32 MFMA acc

__device__ __forceinline__ u16 f2bf(float f) {
    union { float f; uint32_t i; } v; v.f = f;
    uint32_t r = v.i + 0x7fffu + ((v.i >> 16) & 1u);   // round-nearest-even
    return (u16)(r >> 16);
}
// tanh(x) = 1 - 2/(exp2(x*2*log2e)+1) ; ~1e-6 abs err, saturates correctly
__device__ __forceinline__ float fast_tanh(float x) {
    float e = __builtin_amdgcn_exp2f(x * 2.885390081777927f);
    return fmaf(-2.0f, __builtin_amdgcn_rcpf(e + 1.0f), 1.0f);
}

// ---- kernel 1: selector softmax -> folded bf16 A-matrix [row=w*8+l][16] ------
// k0..7 = softmax weights for slots, k8 = sel[10]-sel[8] (consts -1,0,1 folded,
// pairs with basis k8 == 1.0), k9..15 = 0 (K padded to 16 for mfma 32x32x16)
__global__ __launch_bounds__(256) void k_selector(const float* __restrict__ ll,
                                                  u16* __restrict__ selwA) {
    int row = blockIdx.x * 256 + threadIdx.x;   // w*8 + leaf
    if (row >= W8) return;
    const float* p = ll + (size_t)row * 11;
    float v[11]; float m = -1e30f;
    #pragma unroll
    for (int c = 0; c < 11; ++c) { v[c] = p[c]; m = fmaxf(m, v[c]); }
    float s = 0.f;
    #pragma unroll
    for (int c = 0; c < 11; ++c) {
        v[c] = __builtin_amdgcn_exp2f((v[c] - m) * 1.4426950408889634f);
        s += v[c];
    }
    float inv = __builtin_amdgcn_rcpf(s);
    union { u16 h[16]; uint4 q[2]; } o;
    #pragma unroll
    for (int c = 0; c < 8; ++c) o.h[c] = f2bf(v[c] * inv);
    o.h[8] = f2bf((v[10] - v[8]) * inv);
    #pragma unroll
    for (int c = 9; c < 16; ++c) o.h[c] = 0;
    uint4* dst = (uint4*)(selwA + (size_t)row * 16);
    dst[0] = o.q[0]; dst[1] = o.q[1];
}

// ------- kernel 2: transpose+convert out_w (W,D) f32 -> outwt (D,W) bf16 ------
__global__ __launch_bounds__(256) void k_transpose(const float* __restrict__ ow,
                                                   u16* __restrict__ owt) {
    __shared__ float tile[32][33];
    int d0 = blockIdx.x * 32, w0 = blockIdx.y * 32;
    int tx = threadIdx.x, ty = threadIdx.y;   // (32,8)
    #pragma unroll
    for (int i = 0; i < 32; i += 8)
        tile[ty + i][tx] = ow[(size_t)(w0 + ty + i) * DIM + d0 + tx];
    __syncthreads();
    #pragma unroll
    for (int i = 0; i < 32; i += 8)
        owt[(size_t)(d0 + ty + i) * WTR + w0 + tx] = f2bf(tile[tx][ty + i]);
}

// ---- kernel 3: basisTB[t][16] bf16: k0..7=tanh(h@W+b), k8=1.0, k9..15=0 ------
__global__ __launch_bounds__(256) void k_basis(const float* __restrict__ hidden,
                                               const float* __restrict__ slot_w,
                                               const float* __restrict__ slot_b,
                                               u16* __restrict__ basisTB) {
    int t = blockIdx.x, tid = threadIdx.x;
    int d0 = tid * 4;
    float4 hv = *(const float4*)(hidden + (size_t)t * DIM + d0);
    const float* wp = slot_w + (size_t)d0 * 8;   // row d has 8 f32 = 32B
    float4 wa[4], wb[4];
    #pragma unroll
    for (int r = 0; r < 4; ++r) {
        wa[r] = *(const float4*)(wp + r * 8);
        wb[r] = *(const float4*)(wp + r * 8 + 4);
    }
    float h[4] = {hv.x, hv.y, hv.z, hv.w};
    float acc[8] = {0,0,0,0,0,0,0,0};
    #pragma unroll
    for (int r = 0; r < 4; ++r) {
        acc[0] = fmaf(h[r], wa[r].x, acc[0]);
        acc[1] = fmaf(h[r], wa[r].y, acc[1]);
        acc[2] = fmaf(h[r], wa[r].z, acc[2]);
        acc[3] = fmaf(h[r], wa[r].w, acc[3]);
        acc[4] = fmaf(h[r], wb[r].x, acc[4]);
        acc[5] = fmaf(h[r], wb[r].y, acc[5]);
        acc[6] = fmaf(h[r], wb[r].z, acc[6]);
        acc[7] = fmaf(h[r], wb[r].w, acc[7]);
    }
    #pragma unroll
    for (int off = 32; off >= 1; off >>= 1) {
        #pragma unroll
        for (int s = 0; s < 8; ++s) acc[s] += __shfl_down(acc[s], off, 64);
    }
    __shared__ float sm[4][8];
    int wid = tid >> 6, lane = tid & 63;
    if (lane == 0) {
        #pragma unroll
        for (int s = 0; s < 8; ++s) sm[wid][s] = acc[s];
    }
    __syncthreads();
    if (tid < 16) {
        u16 val;
        if (tid < 8) {
            float v = sm[0][tid] + sm[1][tid] + sm[2][tid] + sm[3][tid] + slot_b[tid];
            val = f2bf(fast_tanh(v));
        } else {
            val = (tid == 8) ? (u16)0x3f80 : (u16)0;   // bf16 1.0 at k=8
        }
        basisTB[(size_t)t * 16 + tid] = val;
    }
}

// ---- kernel 4: roots via MFMA einsum + VALU tree -----------------------------
// One mfma_f32_32x32x16_bf16 = 32 leaf-rows (4 trees) x 32 tokens.
// C layout (verified): col=lane&31, row=(reg&3)+8*(reg>>2)+4*(lane>>5).
// half h=0 lanes hold leaves 0-3 of trees 0..3; h=1 hold leaves 4-7.
// One shfl_xor(32) exchange -> each lane owns 2 complete (tree,token) pairs.
// No LDS, no barriers.
#define RT_TOK 512   // tokens per block
__global__ __launch_bounds__(256) void k_roots(const u16* __restrict__ selwA,
                                               const u16* __restrict__ basisTB,
                                               const float* __restrict__ np_,
                                               u16* __restrict__ roots) {
    int tid = threadIdx.x;
    int wid = tid >> 6, lane = tid & 63;
    int h = lane >> 5, c = lane & 31;
    int rowbase = blockIdx.x * 128 + wid * 32;   // grid.x = W8/128 = 256
    int tbase   = rowbase >> 3;                  // 4 trees per wave-tile
    int t0base  = blockIdx.y * RT_TOK;           // grid.y = BSZ/512 = 8

    float lw = np_[0], rw = np_[1], pw = np_[2], dw = np_[3], nb = np_[4];

    // A fragment: row = rowbase + c, k-half = h (8 contiguous bf16 = 16B)
    bhalf8 afrag = *(const bhalf8*)(selwA + (size_t)(rowbase + c) * 16 + h * 8);

    for (int tt = 0; tt < RT_TOK; tt += 32) {
        int t0 = t0base + tt;
        // B fragment: n = t0 + c, k-half = h
        bhalf8 bfrag = *(const bhalf8*)(basisTB + (size_t)(t0 + c) * 16 + h * 8);
        floatx16 accz = {0.f,0.f,0.f,0.f,0.f,0.f,0.f,0.f,
                         0.f,0.f,0.f,0.f,0.f,0.f,0.f,0.f};
        floatx16 cc = __builtin_amdgcn_mfma_f32_32x32x16_bf16(afrag, bfrag, accz, 0, 0, 0);

        // exchange: h0 sends regs 8-15 (trees 2,3 leaves 0-3),
        //           h1 sends regs 0-7  (trees 0,1 leaves 4-7)
        float recv[8];
        #pragma unroll
        for (int i = 0; i < 8; ++i) {
            float send = h ? cc[i] : cc[8 + i];
            recv[i] = __shfl_xor(send, 32, 64);
        }
        float vA[8], vB[8];
        #pragma unroll
        for (int i = 0; i < 4; ++i) {
            vA[i]     = h ? recv[i]     : cc[i];
            vA[4 + i] = h ? cc[8 + i]   : recv[i];
            vB[i]     = h ? recv[4 + i] : cc[4 + i];
            vB[4 + i] = h ? cc[12 + i]  : recv[4 + i];
        }
        // depth-3 tree on both pairs
        #pragma unroll
        for (int lev = 0; lev < 3; ++lev) {
            int n = 4 >> lev;
            #pragma unroll
            for (int i = 0; i < 4; ++i) {
                if (i < n) {
                    float L = vA[2*i], R = vA[2*i+1];
                    float x = fmaf(lw, L, nb);
                    x = fmaf(rw, R, x);
                    x = fmaf(pw, L * R, x);
                    x = fmaf(dw, L - R, x);
                    vA[i] = fast_tanh(x);
                    float L2 = vB[2*i], R2 = vB[2*i+1];
                    float y = fmaf(lw, L2, nb);
                    y = fmaf(rw, R2, y);
                    y = fmaf(pw, L2 * R2, y);
                    y = fmaf(dw, L2 - R2, y);
                    vB[i] = fast_tanh(y);
                }
            }
        }
        // pack: h0 holds trees tbase,tbase+1; h1 holds tbase+2,tbase+3
        uint32_t pk = (uint32_t)f2bf(vA[0]) | ((uint32_t)f2bf(vB[0]) << 16);
        uint32_t other = (uint32_t)__shfl_xor((int)pk, 32, 64);
        if (h == 0) {
            uint2 st; st.x = pk; st.y = other;
            *(uint2*)(roots + (size_t)(t0 + c) * WTR + tbase) = st;
        }
    }
}

// ------- kernel 5: out = roots @ out_w + out_b  (bf16 MFMA, fp32 out) ---------
__device__ __forceinline__ void load16(const void* g, void* lds) {
    __builtin_amdgcn_global_load_lds(
        (const __attribute__((address_space(1))) uint32_t*)g,
        (__attribute__((address_space(3))) uint32_t*)lds, 16, 0, 0);
}

__global__ __launch_bounds__(256) void k_gemm(const u16* __restrict__ A,
                                              const u16* __restrict__ Bt,
                                              const float* __restrict__ out_b,
                                              float* __restrict__ C) {
    __shared__ __align__(16) u16 smA[128 * 32];   // 8KB, row-major [128][32]
    __shared__ __align__(16) u16 smB[64 * 32];    // 4KB, row-major [64][32]
    int tid = threadIdx.x;
    int bm = blockIdx.x * 128, bn = blockIdx.y * 64;
    int lane = tid & 63, wid = tid >> 6;
    int wm = (wid >> 1) * 64, wn = (wid & 1) * 32;

    floatx4 acc[4][2];
    #pragma unroll
    for (int i = 0; i < 4; ++i)
        #pragma unroll
        for (int j = 0; j < 2; ++j) acc[i][j] = (floatx4){0.f, 0.f, 0.f, 0.f};

    int ar = tid >> 2;                 // 0..63
    int ak = (tid & 3) * 8;            // k element offset
    const u16* gA = A  + (size_t)(bm + ar) * KDIM + ak;
    const u16* gB = Bt + (size_t)(bn + ar) * KDIM + ak;
    char* ldA = (char*)smA + tid * 16;
    char* ldB = (char*)smB + tid * 16;

    int col = lane & 15, quad = lane >> 4;
    int aoff = (wm + col) * 32 + quad * 8;
    int boff = (wn + col) * 32 + quad * 8;

    for (int k0 = 0; k0 < KDIM; k0 += 32) {
        __syncthreads();
        load16(gA,              ldA);
        load16(gA + 64 * KDIM,  ldA + 4096);
        load16(gB,              ldB);
        gA += 32; gB += 32;
        __syncthreads();

        bhalf8 af[4], bf[2];
        #pragma unroll
        for (int i = 0; i < 4; ++i)
            af[i] = *(const bhalf8*)(smA + aoff + i * 16 * 32);
        #pragma unroll
        for (int j = 0; j < 2; ++j)
            bf[j] = *(const bhalf8*)(smB + boff + j * 16 * 32);
        #pragma unroll
        for (int i = 0; i < 4; ++i)
            #pragma unroll
            for (int j = 0; j < 2; ++j)
                acc[i][j] = __builtin_amdgcn_mfma_f32_16x16x32_bf16(
                    af[i], bf[j], acc[i][j], 0, 0, 0);
    }

    #pragma unroll
    for (int j = 0; j < 2; ++j) {
        int n = bn + wn + j * 16 + col;
        float bv = out_b[n];
        #pragma unroll
        for (int i = 0; i < 4; ++i) {
            int m0 = bm + wm + i * 16 + quad * 4;
            #pragma unroll
            for (int r = 0; r < 4; ++r)
                C[(size_t)(m0 + r) * DIM + n] = acc[i][j][r] + bv;
        }
    }
}

// ---------------- launcher ----------------------------------------------------
extern "C" void kernel_launch(void* const* d_in, const int* in_sizes, int n_in,
                              void* d_out, int out_size, void* d_ws, size_t ws_size,
                              hipStream_t stream) {
    const float* hidden      = (const float*)d_in[0];
    const float* slot_w      = (const float*)d_in[1];
    const float* slot_b      = (const float*)d_in[2];
    const float* leaf_logits = (const float*)d_in[3];
    const float* node_params = (const float*)d_in[4];
    const float* out_w       = (const float*)d_in[5];
    const float* out_b       = (const float*)d_in[6];
    float* out = (float*)d_out;

    char* ws = (char*)d_ws;
    u16* selwA   = (u16*)ws;                                  // 32768*16*2 = 1048576 B
    u16* basisTB = (u16*)(ws + 1048576);                      // 4096*16*2  = 131072 B
    u16* outwt   = (u16*)(ws + 1048576 + 131072);             // 1024*4096*2= 8388608 B
    u16* roots   = (u16*)(ws + 1048576 + 131072 + 8388608);   // 4096*4096*2= 33554432 B

    k_selector <<<128, 256, 0, stream>>>(leaf_logits, selwA);
    k_transpose<<<dim3(32, 128), dim3(32, 8), 0, stream>>>(out_w, outwt);
    k_basis    <<<BSZ, 256, 0, stream>>>(hidden, slot_w, slot_b, basisTB);
    k_roots    <<<dim3(W8 / 128, BSZ / RT_TOK), 256, 0, stream>>>(selwA, basisTB, node_params, roots);
    k_gemm     <<<dim3(BSZ / 128, DIM / 64), 256, 0, stream>>>(roots, outwt, out_b, out);
}

// Round 4
// 243.110 us; speedup vs baseline: 1.0224x; 1.0224x over previous
//
#include <hip/hip_runtime.h>
#include <stdint.h>

// Problem constants (B=2,S=2048 -> BS=4096). ALL inputs/outputs are FP32.
#define BSZ   4096    // B*S tokens
#define DIM   1024    // D
#define WTR   4096    // W trees
#define KDIM  4096    // GEMM K == W
#define W8    32768   // W*8 leaf-rows

typedef unsigned short u16;
typedef _Float16 half2_t __attribute__((ext_vector_type(2)));
typedef __attribute__((ext_vector_type(8))) short bhalf8;     // 8 x bf16 (4 VGPRs)
typedef __attribute__((ext_vector_type(4))) float floatx4;    // 16x16 MFMA acc

__device__ __forceinline__ u16 f2bf(float f) {
    union { float f; uint32_t i; } v; v.f = f;
    uint32_t r = v.i + 0x7fffu + ((v.i >> 16) & 1u);   // round-nearest-even
    return (u16)(r >> 16);
}
__device__ __forceinline__ u16 f2h(float f) {
    union { _Float16 h; u16 u; } v; v.h = (_Float16)f;  // v_cvt_f16_f32 (RNE)
    return v.u;
}
// tanh(x) = 1 - 2/(exp2(x*2*log2e)+1) ; ~1e-6 abs err, saturates correctly
__device__ __forceinline__ float fast_tanh(float x) {
    float e = __builtin_amdgcn_exp2f(x * 2.885390081777927f);
    return fmaf(-2.0f, __builtin_amdgcn_rcpf(e + 1.0f), 1.0f);
}
// packed f16 dot2 accumulate: c += a.x*b.x + a.y*b.y  (v_dot2_f32_f16)
__device__ __forceinline__ float dot2(uint32_t a, uint32_t b, float c) {
    union { uint32_t u; half2_t h; } ua, ub; ua.u = a; ub.u = b;
#if __has_builtin(__builtin_amdgcn_fdot2)
    return __builtin_amdgcn_fdot2(ua.h, ub.h, c, false);
#else
    c = fmaf((float)ua.h[0], (float)ub.h[0], c);
    return fmaf((float)ua.h[1], (float)ub.h[1], c);
#endif
}

// ---- kernel 0 (fused prep): selector softmax -> f16 pairs; out_w transpose;
//      slot_w transpose (bf16) ------------------------------------------------
// selwA2 row (w*8+l): 16 u16 f16: [w0..w7, bias, 0, 0,0,0,0,0,0]; bias = s10-s8
__global__ __launch_bounds__(256) void k_prep(const float* __restrict__ ll,
                                              u16* __restrict__ selwA2,
                                              const float* __restrict__ ow,
                                              u16* __restrict__ owt,
                                              const float* __restrict__ slot_w,
                                              u16* __restrict__ swT) {
    int bid = blockIdx.x, tid = threadIdx.x;
    if (bid < 128) {                       // ---- selector: 128*256 = 32768 rows
        int row = bid * 256 + tid;
        const float* p = ll + (size_t)row * 11;
        float v[11]; float m = -1e30f;
        #pragma unroll
        for (int c = 0; c < 11; ++c) { v[c] = p[c]; m = fmaxf(m, v[c]); }
        float s = 0.f;
        #pragma unroll
        for (int c = 0; c < 11; ++c) {
            v[c] = __builtin_amdgcn_exp2f((v[c] - m) * 1.4426950408889634f);
            s += v[c];
        }
        float inv = __builtin_amdgcn_rcpf(s);
        union { u16 h[16]; uint4 q[2]; } o;
        #pragma unroll
        for (int c = 0; c < 8; ++c) o.h[c] = f2h(v[c] * inv);
        o.h[8] = f2h((v[10] - v[8]) * inv);
        #pragma unroll
        for (int c = 9; c < 16; ++c) o.h[c] = 0;
        uint4* dst = (uint4*)(selwA2 + (size_t)row * 16);
        dst[0] = o.q[0]; dst[1] = o.q[1];
    } else if (bid < 128 + 4096) {         // ---- out_w (W,D) -> owt (D,W) bf16
        int b = bid - 128;
        int d0 = (b & 31) * 32, w0 = (b >> 5) * 32;
        int tx = tid & 31, ty = tid >> 5;   // (32,8)
        __shared__ float tile[32][33];
        #pragma unroll
        for (int i = 0; i < 32; i += 8)
            tile[ty + i][tx] = ow[(size_t)(w0 + ty + i) * DIM + d0 + tx];
        __syncthreads();
        #pragma unroll
        for (int i = 0; i < 32; i += 8)
            owt[(size_t)(d0 + ty + i) * WTR + w0 + tx] = f2bf(tile[tx][ty + i]);
    } else {                               // ---- slot_w (D,8) -> swT (16,D) bf16
        int b = bid - 128 - 4096;          // 8 blocks x 2048 elems
        for (int it = 0; it < 8; ++it) {
            int idx = b * 2048 + it * 256 + tid;   // 0..16383
            int s = idx >> 10, d = idx & 1023;
            float val = (s < 8) ? slot_w[(size_t)d * 8 + s] : 0.f;
            swT[(size_t)s * DIM + d] = f2bf(val);
        }
    }
}

// ---- kernel 1: basisF16[t][16] f16: n0..7=tanh(h@W+b), n8=1.0, n9..15=0 ------
// one wave per 16 tokens; MFMA 16x16x32 bf16; no LDS, frags straight from global
__global__ __launch_bounds__(64) void k_basis(const float* __restrict__ hidden,
                                              const u16* __restrict__ swT,
                                              const float* __restrict__ slot_b,
                                              u16* __restrict__ basisF16) {
    int m0 = blockIdx.x * 16;
    int lane = threadIdx.x;
    int col = lane & 15, quad = lane >> 4;
    const float* ga = hidden + (size_t)(m0 + col) * DIM + quad * 8;
    const u16*   gb = swT + (size_t)col * DIM + quad * 8;
    floatx4 acc = (floatx4){0.f, 0.f, 0.f, 0.f};
    for (int k0 = 0; k0 < DIM; k0 += 32) {
        float4 a0 = *(const float4*)(ga + k0);
        float4 a1 = *(const float4*)(ga + k0 + 4);
        bhalf8 bf = *(const bhalf8*)(gb + k0);
        bhalf8 af;
        af[0] = (short)f2bf(a0.x); af[1] = (short)f2bf(a0.y);
        af[2] = (short)f2bf(a0.z); af[3] = (short)f2bf(a0.w);
        af[4] = (short)f2bf(a1.x); af[5] = (short)f2bf(a1.y);
        af[6] = (short)f2bf(a1.z); af[7] = (short)f2bf(a1.w);
        acc = __builtin_amdgcn_mfma_f32_16x16x32_bf16(af, bf, acc, 0, 0, 0);
    }
    // C layout: n=col, token=quad*4+r
    float bv = slot_b[col & 7];
    #pragma unroll
    for (int r = 0; r < 4; ++r) {
        int t = m0 + quad * 4 + r;
        u16 val;
        if (col < 8)       val = f2h(fast_tanh(acc[r] + bv));
        else if (col == 8) val = (u16)0x3C00;   // f16 1.0
        else               val = 0;
        basisF16[(size_t)t * 16 + col] = val;
    }
}

// ---- kernel 2: roots = tree(selector @ basis), thread = tree -----------------
// weights: 8 leaves x 5 packed-f16 dwords = 40 VGPRs; einsum = 40 v_dot2_f32_f16
#define TB 64
__global__ __launch_bounds__(256, 4) void k_roots(const u16* __restrict__ selwA2,
                                                  const u16* __restrict__ basisF16,
                                                  const float* __restrict__ np_,
                                                  u16* __restrict__ roots) {
    int w  = blockIdx.x * 256 + threadIdx.x;
    int t0 = blockIdx.y * TB;
    float lw = np_[0], rw = np_[1], pw = np_[2], dw = np_[3], nb = np_[4];

    uint32_t wv[8][5];
    const uint32_t* sp = (const uint32_t*)(selwA2 + (size_t)w * 8 * 16);
    #pragma unroll
    for (int l = 0; l < 8; ++l) {
        uint4 q = *(const uint4*)(sp + l * 8);
        wv[l][0] = q.x; wv[l][1] = q.y; wv[l][2] = q.z; wv[l][3] = q.w;
        wv[l][4] = sp[l * 8 + 4];
    }
    __shared__ uint32_t sb[TB * 8];
    {
        const uint32_t* gbs = (const uint32_t*)basisF16 + (size_t)t0 * 8;
        for (int i = threadIdx.x; i < TB * 8; i += 256) sb[i] = gbs[i];
    }
    __syncthreads();

    for (int tt = 0; tt < TB; ++tt) {
        uint4 q = *(const uint4*)(sb + tt * 8);   // ds_read_b128 broadcast
        uint32_t b4 = sb[tt * 8 + 4];             // (1.0, 0)
        uint32_t bb[5] = {q.x, q.y, q.z, q.w, b4};
        float v[8];
        #pragma unroll
        for (int l = 0; l < 8; ++l) {
            float a = 0.f;
            #pragma unroll
            for (int p = 0; p < 5; ++p) a = dot2(wv[l][p], bb[p], a);
            v[l] = a;
        }
        #pragma unroll
        for (int lev = 0; lev < 3; ++lev) {
            int n = 4 >> lev;
            #pragma unroll
            for (int i = 0; i < 4; ++i) {
                if (i < n) {
                    float L = v[2*i], R = v[2*i+1];
                    float x = fmaf(lw, L, nb);
                    x = fmaf(rw, R, x);
                    x = fmaf(pw, L * R, x);
                    x = fmaf(dw, L - R, x);
                    v[i] = fast_tanh(x);
                }
            }
        }
        roots[(size_t)(t0 + tt) * WTR + w] = f2bf(v[0]);   // coalesced along w
    }
}

// ---- kernel 3: out = roots @ out_w + out_b  (bf16 MFMA, fp32 out) ------------
// m97 shape: BM=128 BN=128 BK=32, 256 thr = 4 waves (2x2), wave tile 64x64
__device__ __forceinline__ void load16(const void* g, void* lds) {
    __builtin_amdgcn_global_load_lds(
        (const __attribute__((address_space(1))) uint32_t*)g,
        (__attribute__((address_space(3))) uint32_t*)lds, 16, 0, 0);
}

__global__ __launch_bounds__(256) void k_gemm(const u16* __restrict__ A,
                                              const u16* __restrict__ Bt,
                                              const float* __restrict__ out_b,
                                              float* __restrict__ C) {
    __shared__ __align__(16) u16 smA[128 * 32];   // 8KB
    __shared__ __align__(16) u16 smB[128 * 32];   // 8KB
    int tid = threadIdx.x;
    int bm = blockIdx.x * 128, bn = blockIdx.y * 128;
    int lane = tid & 63, wid = tid >> 6;
    int wm = (wid >> 1) * 64, wn = (wid & 1) * 64;

    floatx4 acc[4][4];
    #pragma unroll
    for (int i = 0; i < 4; ++i)
        #pragma unroll
        for (int j = 0; j < 4; ++j) acc[i][j] = (floatx4){0.f, 0.f, 0.f, 0.f};

    int ar = tid >> 2;                 // 0..63
    int ak = (tid & 3) * 8;
    const u16* gA = A  + (size_t)(bm + ar) * KDIM + ak;
    const u16* gB = Bt + (size_t)(bn + ar) * KDIM + ak;
    char* ldA = (char*)smA + tid * 16;
    char* ldB = (char*)smB + tid * 16;

    int col = lane & 15, quad = lane >> 4;
    int aoff = (wm + col) * 32 + quad * 8;
    int boff = (wn + col) * 32 + quad * 8;

    for (int k0 = 0; k0 < KDIM; k0 += 32) {
        __syncthreads();
        load16(gA,              ldA);
        load16(gA + 64 * KDIM,  ldA + 4096);
        load16(gB,              ldB);
        load16(gB + 64 * KDIM,  ldB + 4096);
        gA += 32; gB += 32;
        __syncthreads();

        bhalf8 af[4], bf[4];
        #pragma unroll
        for (int i = 0; i < 4; ++i)
            af[i] = *(const bhalf8*)(smA + aoff + i * 16 * 32);
        #pragma unroll
        for (int j = 0; j < 4; ++j)
            bf[j] = *(const bhalf8*)(smB + boff + j * 16 * 32);
        #pragma unroll
        for (int i = 0; i < 4; ++i)
            #pragma unroll
            for (int j = 0; j < 4; ++j)
                acc[i][j] = __builtin_amdgcn_mfma_f32_16x16x32_bf16(
                    af[i], bf[j], acc[i][j], 0, 0, 0);
    }

    #pragma unroll
    for (int j = 0; j < 4; ++j) {
        int n = bn + wn + j * 16 + col;
        float bv = out_b[n];
        #pragma unroll
        for (int i = 0; i < 4; ++i) {
            int m0 = bm + wm + i * 16 + quad * 4;
            #pragma unroll
            for (int r = 0; r < 4; ++r)
                C[(size_t)(m0 + r) * DIM + n] = acc[i][j][r] + bv;
        }
    }
}

// ---------------- launcher ----------------------------------------------------
extern "C" void kernel_launch(void* const* d_in, const int* in_sizes, int n_in,
                              void* d_out, int out_size, void* d_ws, size_t ws_size,
                              hipStream_t stream) {
    const float* hidden      = (const float*)d_in[0];
    const float* slot_w      = (const float*)d_in[1];
    const float* slot_b      = (const float*)d_in[2];
    const float* leaf_logits = (const float*)d_in[3];
    const float* node_params = (const float*)d_in[4];
    const float* out_w       = (const float*)d_in[5];
    const float* out_b       = (const float*)d_in[6];
    float* out = (float*)d_out;

    char* ws = (char*)d_ws;
    u16* selwA2   = (u16*)ws;                         // 32768*32B   = 1048576
    u16* basisF16 = (u16*)(ws + 1048576);             // 4096*32B    = 131072
    u16* swT      = (u16*)(ws + 1179648);             // 16*1024*2   = 32768
    u16* outwt    = (u16*)(ws + 1212416);             // 1024*4096*2 = 8388608
    u16* roots    = (u16*)(ws + 9601024);             // 4096*4096*2 = 33554432

    k_prep <<<128 + 4096 + 8, 256, 0, stream>>>(leaf_logits, selwA2, out_w, outwt, slot_w, swT);
    k_basis<<<BSZ / 16, 64, 0, stream>>>(hidden, swT, slot_b, basisF16);
    k_roots<<<dim3(WTR / 256, BSZ / TB), 256, 0, stream>>>(selwA2, basisF16, node_params, roots);
    k_gemm <<<dim3(BSZ / 128, DIM / 128), 256, 0, stream>>>(roots, outwt, out_b, out);
}